// Round 3
// baseline (220.037 us; speedup 1.0000x reference)
//
#include <hip/hip_runtime.h>

namespace {
constexpr int kB = 32;
constexpr int kN = 1024;
constexpr int kT = 64;
constexpr int kD = 32;
constexpr int kM = 1088;  // N + T

constexpr int BLK_NN = kB * 8 * 8;  // 2048 blocks, 128x128 tiles of spatial gram
constexpr int BLK_ST = kB * 16;     // 512 blocks, 64 spatial rows x 64 temporal cols
constexpr int BLK_TS = kB * 16;     // 512 blocks, 64 temporal rows x 64 spatial cols
constexpr int BLK_TT = kB;          // 32 blocks, 64x64 temporal gram
constexpr int BLK_TOTAL = BLK_NN + BLK_ST + BLK_TS + BLK_TT;  // 3104

// 128x128 gram tile: A row-major padded to 36 (row stride 36 == 4 mod 32 -> 2-way
// bank alias on column reads, free per m136), Bt transposed [k][c] padded to 132.
struct SMemGram128 {
  float A[128][36];
  float Bt[32][132];
};
struct SMemGram64 {  // TT quadrant (only 64 temporal nodes)
  float A[64][36];
  float Bt[32][68];
};
struct SMemMLP {
  union {
    struct { float raw1[64][36]; float raw2[64][36]; } r;  // staged inputs
    struct { float EA[64][36]; float EBt[32][68]; } e;     // exp(-proj)
  } u;
  float w1[64][32];
  float w2v[32];
  float b1v[32];
  float b2v;
};
union SMem { SMemGram128 g; SMemGram64 g64; SMemMLP m; };
}  // namespace

// tanh(relu(x)); stable for large x (exp->inf => rcp->0 => result 1).
__device__ __forceinline__ float tanh_relu(float x) {
  if (x <= 0.f) return 0.f;
  float e = __expf(2.f * x);
  return 1.f - 2.f * __builtin_amdgcn_rcpf(e + 1.f);
}

__global__ void __launch_bounds__(256)
adj_kernel(const float* __restrict__ sp, const float* __restrict__ tp,
           const float* __restrict__ st_w1, const float* __restrict__ st_b1,
           const float* __restrict__ st_w2, const float* __restrict__ st_b2,
           const float* __restrict__ ts_w1, const float* __restrict__ ts_b1,
           const float* __restrict__ ts_w2, const float* __restrict__ ts_b2,
           float* __restrict__ out) {
  __shared__ SMem sm;
  const int bid = blockIdx.x;
  const int tid = threadIdx.x;
  const int tx = tid & 15;  // 16 col-groups
  const int ty = tid >> 4;  // 16 row-groups

  if (bid < BLK_NN) {
    // ---------------- NN: 128x128 spatial gram, 8x8 per thread ----------------
    const int b = bid >> 6;
    const int t = bid & 63;
    const int r0 = (t >> 3) * 128;
    const int c0 = (t & 7) * 128;
    const float* rowp = sp + ((size_t)b * kN + r0) * kD;
    const float* colp = sp + ((size_t)b * kN + c0) * kD;
    // Stage 128 rows x 32 k each side (1024 float4 per side).
    for (int q = tid; q < 1024; q += 256) {
      const int r = q >> 3, c = (q & 7) * 4;
      *(float4*)&sm.g.A[r][c] = ((const float4*)rowp)[q];
      const float4 w = ((const float4*)colp)[q];
      sm.g.Bt[c + 0][r] = w.x;
      sm.g.Bt[c + 1][r] = w.y;
      sm.g.Bt[c + 2][r] = w.z;
      sm.g.Bt[c + 3][r] = w.w;
    }
    __syncthreads();
    // Thread tile: rows {ty*4..+3, 64+ty*4..+3}, cols {tx*4..+3, 64+tx*4..+3}.
    float acc[8][8] = {};
    #pragma unroll
    for (int k4 = 0; k4 < 8; ++k4) {
      float4 a0[4], a1[4];
      #pragma unroll
      for (int i = 0; i < 4; ++i) {
        a0[i] = *(const float4*)&sm.g.A[ty * 4 + i][k4 * 4];
        a1[i] = *(const float4*)&sm.g.A[64 + ty * 4 + i][k4 * 4];
      }
      #pragma unroll
      for (int kk = 0; kk < 4; ++kk) {
        const int k = k4 * 4 + kk;
        const float4 b0 = *(const float4*)&sm.g.Bt[k][tx * 4];
        const float4 b1 = *(const float4*)&sm.g.Bt[k][64 + tx * 4];
        #pragma unroll
        for (int i = 0; i < 4; ++i) {
          const float av0 = (&a0[i].x)[kk];
          const float av1 = (&a1[i].x)[kk];
          acc[i][0] = fmaf(av0, b0.x, acc[i][0]);
          acc[i][1] = fmaf(av0, b0.y, acc[i][1]);
          acc[i][2] = fmaf(av0, b0.z, acc[i][2]);
          acc[i][3] = fmaf(av0, b0.w, acc[i][3]);
          acc[i][4] = fmaf(av0, b1.x, acc[i][4]);
          acc[i][5] = fmaf(av0, b1.y, acc[i][5]);
          acc[i][6] = fmaf(av0, b1.z, acc[i][6]);
          acc[i][7] = fmaf(av0, b1.w, acc[i][7]);
          acc[4 + i][0] = fmaf(av1, b0.x, acc[4 + i][0]);
          acc[4 + i][1] = fmaf(av1, b0.y, acc[4 + i][1]);
          acc[4 + i][2] = fmaf(av1, b0.z, acc[4 + i][2]);
          acc[4 + i][3] = fmaf(av1, b0.w, acc[4 + i][3]);
          acc[4 + i][4] = fmaf(av1, b1.x, acc[4 + i][4]);
          acc[4 + i][5] = fmaf(av1, b1.y, acc[4 + i][5]);
          acc[4 + i][6] = fmaf(av1, b1.z, acc[4 + i][6]);
          acc[4 + i][7] = fmaf(av1, b1.w, acc[4 + i][7]);
        }
      }
    }
    const size_t base = (size_t)b * kM * kM + (size_t)c0 + tx * 4;
    #pragma unroll
    for (int h = 0; h < 2; ++h) {
      #pragma unroll
      for (int i = 0; i < 4; ++i) {
        const int r = r0 + h * 64 + ty * 4 + i;
        const float* a = acc[h * 4 + i];
        float4 o0, o1;
        o0.x = tanh_relu(a[0]); o0.y = tanh_relu(a[1]);
        o0.z = tanh_relu(a[2]); o0.w = tanh_relu(a[3]);
        o1.x = tanh_relu(a[4]); o1.y = tanh_relu(a[5]);
        o1.z = tanh_relu(a[6]); o1.w = tanh_relu(a[7]);
        *(float4*)&out[base + (size_t)r * kM] = o0;
        *(float4*)&out[base + (size_t)r * kM + 64] = o1;
      }
    }
  } else if (bid >= BLK_NN + BLK_ST + BLK_TS) {
    // ---------------- TT: 64x64 temporal gram, 4x4 per thread ----------------
    const int b = bid - (BLK_NN + BLK_ST + BLK_TS);
    const float* rowp = tp + (size_t)b * kT * kD;
    for (int q = tid; q < 512; q += 256) {
      const int r = q >> 3, c = (q & 7) * 4;
      const float4 v = ((const float4*)rowp)[q];
      *(float4*)&sm.g64.A[r][c] = v;
      sm.g64.Bt[c + 0][r] = v.x;
      sm.g64.Bt[c + 1][r] = v.y;
      sm.g64.Bt[c + 2][r] = v.z;
      sm.g64.Bt[c + 3][r] = v.w;
    }
    __syncthreads();
    float acc[4][4] = {};
    #pragma unroll
    for (int k4 = 0; k4 < 8; ++k4) {
      float4 a4[4];
      #pragma unroll
      for (int i = 0; i < 4; ++i)
        a4[i] = *(const float4*)&sm.g64.A[ty * 4 + i][k4 * 4];
      #pragma unroll
      for (int kk = 0; kk < 4; ++kk) {
        const float4 b4 = *(const float4*)&sm.g64.Bt[k4 * 4 + kk][tx * 4];
        #pragma unroll
        for (int i = 0; i < 4; ++i) {
          const float av = (&a4[i].x)[kk];
          acc[i][0] = fmaf(av, b4.x, acc[i][0]);
          acc[i][1] = fmaf(av, b4.y, acc[i][1]);
          acc[i][2] = fmaf(av, b4.z, acc[i][2]);
          acc[i][3] = fmaf(av, b4.w, acc[i][3]);
        }
      }
    }
    const size_t base = (size_t)b * kM * kM + (size_t)kN + tx * 4;
    #pragma unroll
    for (int i = 0; i < 4; ++i) {
      const int r = kN + ty * 4 + i;
      float4 o;
      o.x = tanh_relu(acc[i][0]);
      o.y = tanh_relu(acc[i][1]);
      o.z = tanh_relu(acc[i][2]);
      o.w = tanh_relu(acc[i][3]);
      *(float4*)&out[base + (size_t)r * kM] = o;
    }
  } else {
    // ---------------- ST / TS: rank-structured MLP, 64x64 per block ----------
    int i = bid - BLK_NN;
    int b, r0, c0;
    const float *rowp, *colp, *w1, *b1, *w2, *b2;
    if (i < BLK_ST) {
      b = i >> 4;
      r0 = (i & 15) * 64; c0 = kN;
      rowp = sp + ((size_t)b * kN + r0) * kD;  // spatial rows (x1)
      colp = tp + (size_t)b * kT * kD;         // temporal cols (x2)
      w1 = st_w1; b1 = st_b1; w2 = st_w2; b2 = st_b2;
    } else {
      i -= BLK_ST;
      b = i >> 4;
      r0 = kN; c0 = (i & 15) * 64;
      rowp = tp + (size_t)b * kT * kD;          // temporal rows (x1)
      colp = sp + ((size_t)b * kN + c0) * kD;   // spatial cols (x2)
      w1 = ts_w1; b1 = ts_b1; w2 = ts_w2; b2 = ts_b2;
    }
    for (int q = tid; q < 512; q += 256) {
      const int r = q >> 3, c = (q & 7) * 4;
      *(float4*)&sm.m.u.r.raw1[r][c] = ((const float4*)rowp)[q];
      *(float4*)&sm.m.u.r.raw2[r][c] = ((const float4*)colp)[q];
      ((float4*)sm.m.w1)[q] = ((const float4*)w1)[q];
    }
    if (tid < kD) { sm.m.w2v[tid] = w2[tid]; sm.m.b1v[tid] = b1[tid]; }
    if (tid == 0) sm.m.b2v = b2[0];
    __syncthreads();
    // Projections into registers: thread -> (row pr, 8 d's starting at d0).
    const int pr = tid >> 2;
    const int d0 = (tid & 3) * 8;
    float pa[8], pb[8];
    #pragma unroll
    for (int q = 0; q < 8; ++q) { pa[q] = 0.f; pb[q] = sm.m.b1v[d0 + q]; }
    #pragma unroll 4
    for (int k = 0; k < kD; ++k) {
      const float s1 = sm.m.u.r.raw1[pr][k];
      const float s2 = sm.m.u.r.raw2[pr][k];
      #pragma unroll
      for (int q = 0; q < 8; ++q) {
        pa[q] = fmaf(s1, sm.m.w1[k][d0 + q], pa[q]);
        pb[q] = fmaf(s2, sm.m.w1[kD + k][d0 + q], pb[q]);
      }
    }
    const float b2s = sm.m.b2v;
    __syncthreads();  // raw reads done; safe to overwrite the union
    #pragma unroll
    for (int q = 0; q < 8; ++q) {
      sm.m.u.e.EA[pr][d0 + q] = __expf(-pa[q]);
      sm.m.u.e.EBt[d0 + q][pr] = __expf(-pb[q]);
    }
    __syncthreads();
    // sigmoid(a+b+b1) = rcp(1 + exp(-a)*exp(-(b+b1))): 1 transcendental/elem.
    float acc[4][4];
    #pragma unroll
    for (int ii = 0; ii < 4; ++ii)
      #pragma unroll
      for (int jj = 0; jj < 4; ++jj) acc[ii][jj] = b2s;
    #pragma unroll
    for (int d4 = 0; d4 < 8; ++d4) {
      float4 ea4[4];
      #pragma unroll
      for (int ii = 0; ii < 4; ++ii)
        ea4[ii] = *(const float4*)&sm.m.u.e.EA[ty * 4 + ii][d4 * 4];
      #pragma unroll
      for (int dd = 0; dd < 4; ++dd) {
        const int d = d4 * 4 + dd;
        const float4 eb4 = *(const float4*)&sm.m.u.e.EBt[d][tx * 4];
        const float w2d = sm.m.w2v[d];
        #pragma unroll
        for (int ii = 0; ii < 4; ++ii) {
          const float eav = (&ea4[ii].x)[dd];
          acc[ii][0] = fmaf(w2d, __builtin_amdgcn_rcpf(fmaf(eav, eb4.x, 1.f)), acc[ii][0]);
          acc[ii][1] = fmaf(w2d, __builtin_amdgcn_rcpf(fmaf(eav, eb4.y, 1.f)), acc[ii][1]);
          acc[ii][2] = fmaf(w2d, __builtin_amdgcn_rcpf(fmaf(eav, eb4.z, 1.f)), acc[ii][2]);
          acc[ii][3] = fmaf(w2d, __builtin_amdgcn_rcpf(fmaf(eav, eb4.w, 1.f)), acc[ii][3]);
        }
      }
    }
    const size_t base = (size_t)b * kM * kM + (size_t)c0 + tx * 4;
    #pragma unroll
    for (int ii = 0; ii < 4; ++ii) {
      const int r = r0 + ty * 4 + ii;
      float4 o;
      o.x = tanh_relu(acc[ii][0]);
      o.y = tanh_relu(acc[ii][1]);
      o.z = tanh_relu(acc[ii][2]);
      o.w = tanh_relu(acc[ii][3]);
      *(float4*)&out[base + (size_t)r * kM] = o;
    }
  }
}

extern "C" void kernel_launch(void* const* d_in, const int* in_sizes, int n_in,
                              void* d_out, int out_size, void* d_ws, size_t ws_size,
                              hipStream_t stream) {
  const float* sp    = (const float*)d_in[0];
  const float* tp    = (const float*)d_in[1];
  const float* st_w1 = (const float*)d_in[2];
  const float* st_b1 = (const float*)d_in[3];
  const float* st_w2 = (const float*)d_in[4];
  const float* st_b2 = (const float*)d_in[5];
  const float* ts_w1 = (const float*)d_in[6];
  const float* ts_b1 = (const float*)d_in[7];
  const float* ts_w2 = (const float*)d_in[8];
  const float* ts_b2 = (const float*)d_in[9];
  float* out = (float*)d_out;
  (void)in_sizes; (void)n_in; (void)out_size; (void)d_ws; (void)ws_size;
  adj_kernel<<<dim3(BLK_TOTAL), dim3(256), 0, stream>>>(
      sp, tp, st_w1, st_b1, st_w2, st_b2, ts_w1, ts_b1, ts_w2, ts_b2, out);
}

// Round 4
// 219.454 us; speedup vs baseline: 1.0027x; 1.0027x over previous
//
#include <hip/hip_runtime.h>

namespace {
constexpr int kB = 32;
constexpr int kN = 1024;
constexpr int kT = 64;
constexpr int kD = 32;
constexpr int kM = 1088;  // N + T

constexpr int BLK_NN = kB * 8 * 8;        // 2048 blocks, 128x128 NN tiles
constexpr int BLK_TT = kB;                // 32 blocks, 64x64 TT gram
constexpr int BLK_GRAM = BLK_NN + BLK_TT; // 2080
constexpr int BLK_ST = kB * 16;           // 512 blocks per MLP quadrant
constexpr int BLK_MLP = 2 * BLK_ST;       // 1024

// Row stride 36 floats == 4 mod 32 -> 2-way bank alias on column walks (free).
struct SMemGram128 { float A[128][36]; float Bt[32][132]; };
struct SMemGram64  { float A[64][36];  float Bt[32][68];  };
struct SMemMLP {
  union {
    struct { float raw1[64][36]; float raw2[64][36]; } r;  // staged inputs
    struct { float EA[64][36]; float EBt[32][68]; } e;     // exp(-proj)
  } u;
  float w1[64][32];
  float w2v[32];
  float b1v[32];
  float b2v;
};
}  // namespace

// All component accesses explicit (no (&v.x)[k] address-of patterns -> SROA-safe).
#define FMA4(ACC, AV, B, C)            \
  ACC = fmaf(AV.x, B[0].C, ACC);       \
  ACC = fmaf(AV.y, B[1].C, ACC);       \
  ACC = fmaf(AV.z, B[2].C, ACC);       \
  ACC = fmaf(AV.w, B[3].C, ACC);

#define SIGSTEP(AROW, EAV, EBD, W2D)                                            \
  AROW[0] = fmaf(W2D, __builtin_amdgcn_rcpf(fmaf(EAV, EBD.x, 1.f)), AROW[0]);   \
  AROW[1] = fmaf(W2D, __builtin_amdgcn_rcpf(fmaf(EAV, EBD.y, 1.f)), AROW[1]);   \
  AROW[2] = fmaf(W2D, __builtin_amdgcn_rcpf(fmaf(EAV, EBD.z, 1.f)), AROW[2]);   \
  AROW[3] = fmaf(W2D, __builtin_amdgcn_rcpf(fmaf(EAV, EBD.w, 1.f)), AROW[3]);

// tanh(relu(x)), branchless; exact 0 at x<=0 (exp(0)=1, rcp(2)=.5), ->1 for large x.
__device__ __forceinline__ float tanh_relu(float x) {
  const float xp = fmaxf(x, 0.f);
  const float e = __expf(2.f * xp);
  return 1.f - 2.f * __builtin_amdgcn_rcpf(e + 1.f);
}

__global__ void __launch_bounds__(256)
gram_kernel(const float* __restrict__ sp, const float* __restrict__ tp,
            float* __restrict__ out) {
  __shared__ union { SMemGram128 g; SMemGram64 g64; } sm;
  const int bid = blockIdx.x;
  const int tid = threadIdx.x;
  const int tx = tid & 15;
  const int ty = tid >> 4;

  if (bid < BLK_NN) {
    // -------- NN: 128x128 spatial gram, 8x8 per thread --------
    const int b = bid >> 6;
    const int t = bid & 63;
    const int r0 = (t >> 3) * 128;
    const int c0 = (t & 7) * 128;
    const float* rowp = sp + ((size_t)b * kN + r0) * kD;
    const float* colp = sp + ((size_t)b * kN + c0) * kD;
    for (int q = tid; q < 1024; q += 256) {
      const int r = q >> 3, c = (q & 7) * 4;
      *(float4*)&sm.g.A[r][c] = ((const float4*)rowp)[q];
      const float4 w = ((const float4*)colp)[q];
      sm.g.Bt[c + 0][r] = w.x;
      sm.g.Bt[c + 1][r] = w.y;
      sm.g.Bt[c + 2][r] = w.z;
      sm.g.Bt[c + 3][r] = w.w;
    }
    __syncthreads();
    float acc[8][8] = {};
    #pragma unroll
    for (int k4 = 0; k4 < 8; ++k4) {
      float4 b0[4], b1[4];
      #pragma unroll
      for (int kk = 0; kk < 4; ++kk) {
        b0[kk] = *(const float4*)&sm.g.Bt[k4 * 4 + kk][tx * 4];
        b1[kk] = *(const float4*)&sm.g.Bt[k4 * 4 + kk][64 + tx * 4];
      }
      #pragma unroll
      for (int i = 0; i < 8; ++i) {  // rows ty*4+i (i<4) and 64+ty*4+(i-4)
        const int row = (i & 4) * 16 + ty * 4 + (i & 3);
        const float4 a = *(const float4*)&sm.g.A[row][k4 * 4];
        FMA4(acc[i][0], a, b0, x)
        FMA4(acc[i][1], a, b0, y)
        FMA4(acc[i][2], a, b0, z)
        FMA4(acc[i][3], a, b0, w)
        FMA4(acc[i][4], a, b1, x)
        FMA4(acc[i][5], a, b1, y)
        FMA4(acc[i][6], a, b1, z)
        FMA4(acc[i][7], a, b1, w)
      }
    }
    const size_t base = (size_t)b * kM * kM + (size_t)c0 + tx * 4;
    #pragma unroll
    for (int i = 0; i < 8; ++i) {
      const int r = r0 + (i & 4) * 16 + ty * 4 + (i & 3);
      float4 o0, o1;
      o0.x = tanh_relu(acc[i][0]); o0.y = tanh_relu(acc[i][1]);
      o0.z = tanh_relu(acc[i][2]); o0.w = tanh_relu(acc[i][3]);
      o1.x = tanh_relu(acc[i][4]); o1.y = tanh_relu(acc[i][5]);
      o1.z = tanh_relu(acc[i][6]); o1.w = tanh_relu(acc[i][7]);
      *(float4*)&out[base + (size_t)r * kM] = o0;
      *(float4*)&out[base + (size_t)r * kM + 64] = o1;
    }
  } else {
    // -------- TT: 64x64 temporal gram, 4x4 per thread --------
    const int b = bid - BLK_NN;
    const float* rowp = tp + (size_t)b * kT * kD;
    for (int q = tid; q < 512; q += 256) {
      const int r = q >> 3, c = (q & 7) * 4;
      const float4 v = ((const float4*)rowp)[q];
      *(float4*)&sm.g64.A[r][c] = v;
      sm.g64.Bt[c + 0][r] = v.x;
      sm.g64.Bt[c + 1][r] = v.y;
      sm.g64.Bt[c + 2][r] = v.z;
      sm.g64.Bt[c + 3][r] = v.w;
    }
    __syncthreads();
    float acc[4][4] = {};
    #pragma unroll
    for (int k4 = 0; k4 < 8; ++k4) {
      float4 b4[4];
      #pragma unroll
      for (int kk = 0; kk < 4; ++kk)
        b4[kk] = *(const float4*)&sm.g64.Bt[k4 * 4 + kk][tx * 4];
      #pragma unroll
      for (int i = 0; i < 4; ++i) {
        const float4 a = *(const float4*)&sm.g64.A[ty * 4 + i][k4 * 4];
        FMA4(acc[i][0], a, b4, x)
        FMA4(acc[i][1], a, b4, y)
        FMA4(acc[i][2], a, b4, z)
        FMA4(acc[i][3], a, b4, w)
      }
    }
    const size_t base = (size_t)b * kM * kM + (size_t)kN + tx * 4;
    #pragma unroll
    for (int i = 0; i < 4; ++i) {
      const int r = kN + ty * 4 + i;
      float4 o;
      o.x = tanh_relu(acc[i][0]);
      o.y = tanh_relu(acc[i][1]);
      o.z = tanh_relu(acc[i][2]);
      o.w = tanh_relu(acc[i][3]);
      *(float4*)&out[base + (size_t)r * kM] = o;
    }
  }
}

__global__ void __launch_bounds__(256)
mlp_kernel(const float* __restrict__ sp, const float* __restrict__ tp,
           const float* __restrict__ st_w1, const float* __restrict__ st_b1,
           const float* __restrict__ st_w2, const float* __restrict__ st_b2,
           const float* __restrict__ ts_w1, const float* __restrict__ ts_b1,
           const float* __restrict__ ts_w2, const float* __restrict__ ts_b2,
           float* __restrict__ out) {
  __shared__ SMemMLP sm;
  const int bid = blockIdx.x;
  const int tid = threadIdx.x;
  const int tx = tid & 15;
  const int ty = tid >> 4;

  int b, r0, c0;
  const float *rowp, *colp, *w1, *b1, *w2, *b2;
  if (bid < BLK_ST) {
    b = bid >> 4;
    r0 = (bid & 15) * 64; c0 = kN;
    rowp = sp + ((size_t)b * kN + r0) * kD;  // spatial rows (x1)
    colp = tp + (size_t)b * kT * kD;         // temporal cols (x2)
    w1 = st_w1; b1 = st_b1; w2 = st_w2; b2 = st_b2;
  } else {
    const int i = bid - BLK_ST;
    b = i >> 4;
    r0 = kN; c0 = (i & 15) * 64;
    rowp = tp + (size_t)b * kT * kD;          // temporal rows (x1)
    colp = sp + ((size_t)b * kN + c0) * kD;   // spatial cols (x2)
    w1 = ts_w1; b1 = ts_b1; w2 = ts_w2; b2 = ts_b2;
  }
  for (int q = tid; q < 512; q += 256) {
    const int r = q >> 3, c = (q & 7) * 4;
    *(float4*)&sm.u.r.raw1[r][c] = ((const float4*)rowp)[q];
    *(float4*)&sm.u.r.raw2[r][c] = ((const float4*)colp)[q];
    ((float4*)sm.w1)[q] = ((const float4*)w1)[q];
  }
  if (tid < kD) { sm.w2v[tid] = w2[tid]; sm.b1v[tid] = b1[tid]; }
  if (tid == 0) sm.b2v = b2[0];
  __syncthreads();
  // Projections: thread -> (row pr, 8 hidden dims starting at d0).
  const int pr = tid >> 2;
  const int d0 = (tid & 3) * 8;
  float pa[8], pb[8];
  #pragma unroll
  for (int q = 0; q < 8; ++q) { pa[q] = 0.f; pb[q] = sm.b1v[d0 + q]; }
  for (int k = 0; k < kD; ++k) {
    const float s1 = sm.u.r.raw1[pr][k];
    const float s2 = sm.u.r.raw2[pr][k];
    const float4 wa0 = *(const float4*)&sm.w1[k][d0];
    const float4 wa1 = *(const float4*)&sm.w1[k][d0 + 4];
    const float4 wb0 = *(const float4*)&sm.w1[kD + k][d0];
    const float4 wb1 = *(const float4*)&sm.w1[kD + k][d0 + 4];
    pa[0] = fmaf(s1, wa0.x, pa[0]); pa[1] = fmaf(s1, wa0.y, pa[1]);
    pa[2] = fmaf(s1, wa0.z, pa[2]); pa[3] = fmaf(s1, wa0.w, pa[3]);
    pa[4] = fmaf(s1, wa1.x, pa[4]); pa[5] = fmaf(s1, wa1.y, pa[5]);
    pa[6] = fmaf(s1, wa1.z, pa[6]); pa[7] = fmaf(s1, wa1.w, pa[7]);
    pb[0] = fmaf(s2, wb0.x, pb[0]); pb[1] = fmaf(s2, wb0.y, pb[1]);
    pb[2] = fmaf(s2, wb0.z, pb[2]); pb[3] = fmaf(s2, wb0.w, pb[3]);
    pb[4] = fmaf(s2, wb1.x, pb[4]); pb[5] = fmaf(s2, wb1.y, pb[5]);
    pb[6] = fmaf(s2, wb1.z, pb[6]); pb[7] = fmaf(s2, wb1.w, pb[7]);
  }
  const float b2s = sm.b2v;
  __syncthreads();  // raw reads done; safe to overwrite the union
  #pragma unroll
  for (int q = 0; q < 8; ++q) {
    sm.u.e.EA[pr][d0 + q] = __expf(-pa[q]);
    sm.u.e.EBt[d0 + q][pr] = __expf(-pb[q]);
  }
  __syncthreads();
  // sigmoid(a+b+b1) = rcp(1 + exp(-a)*exp(-(b+b1))): 1 transcendental per term.
  float acc[4][4];
  #pragma unroll
  for (int ii = 0; ii < 4; ++ii) {
    acc[ii][0] = b2s; acc[ii][1] = b2s; acc[ii][2] = b2s; acc[ii][3] = b2s;
  }
  #pragma unroll
  for (int d4 = 0; d4 < 8; ++d4) {
    float4 ea[4];
    #pragma unroll
    for (int ii = 0; ii < 4; ++ii)
      ea[ii] = *(const float4*)&sm.u.e.EA[ty * 4 + ii][d4 * 4];
    const float4 eb0 = *(const float4*)&sm.u.e.EBt[d4 * 4 + 0][tx * 4];
    const float4 eb1 = *(const float4*)&sm.u.e.EBt[d4 * 4 + 1][tx * 4];
    const float4 eb2 = *(const float4*)&sm.u.e.EBt[d4 * 4 + 2][tx * 4];
    const float4 eb3 = *(const float4*)&sm.u.e.EBt[d4 * 4 + 3][tx * 4];
    const float w20 = sm.w2v[d4 * 4 + 0];
    const float w21 = sm.w2v[d4 * 4 + 1];
    const float w22 = sm.w2v[d4 * 4 + 2];
    const float w23 = sm.w2v[d4 * 4 + 3];
    #pragma unroll
    for (int ii = 0; ii < 4; ++ii) {
      SIGSTEP(acc[ii], ea[ii].x, eb0, w20)
      SIGSTEP(acc[ii], ea[ii].y, eb1, w21)
      SIGSTEP(acc[ii], ea[ii].z, eb2, w22)
      SIGSTEP(acc[ii], ea[ii].w, eb3, w23)
    }
  }
  const size_t base = (size_t)b * kM * kM + (size_t)c0 + tx * 4;
  #pragma unroll
  for (int ii = 0; ii < 4; ++ii) {
    const int r = r0 + ty * 4 + ii;
    float4 o;
    o.x = tanh_relu(acc[ii][0]);
    o.y = tanh_relu(acc[ii][1]);
    o.z = tanh_relu(acc[ii][2]);
    o.w = tanh_relu(acc[ii][3]);
    *(float4*)&out[base + (size_t)r * kM] = o;
  }
}

extern "C" void kernel_launch(void* const* d_in, const int* in_sizes, int n_in,
                              void* d_out, int out_size, void* d_ws, size_t ws_size,
                              hipStream_t stream) {
  const float* sp    = (const float*)d_in[0];
  const float* tp    = (const float*)d_in[1];
  const float* st_w1 = (const float*)d_in[2];
  const float* st_b1 = (const float*)d_in[3];
  const float* st_w2 = (const float*)d_in[4];
  const float* st_b2 = (const float*)d_in[5];
  const float* ts_w1 = (const float*)d_in[6];
  const float* ts_b1 = (const float*)d_in[7];
  const float* ts_w2 = (const float*)d_in[8];
  const float* ts_b2 = (const float*)d_in[9];
  float* out = (float*)d_out;
  (void)in_sizes; (void)n_in; (void)out_size; (void)d_ws; (void)ws_size;
  gram_kernel<<<dim3(BLK_GRAM), dim3(256), 0, stream>>>(sp, tp, out);
  mlp_kernel<<<dim3(BLK_MLP), dim3(256), 0, stream>>>(
      sp, tp, st_w1, st_b1, st_w2, st_b2, ts_w1, ts_b1, ts_w2, ts_b2, out);
}

// Round 5
// 203.406 us; speedup vs baseline: 1.0818x; 1.0789x over previous
//
#include <hip/hip_runtime.h>

namespace {
constexpr int kB = 32;
constexpr int kN = 1024;
constexpr int kT = 64;
constexpr int kD = 32;
constexpr int kM = 1088;  // N + T

// Block layout (MLP first so its VALU work overlaps the NN write drain):
// [0, 512)      ST   64 spatial rows x 64 temporal cols
// [512, 1024)   TS   64 temporal rows x 64 spatial cols
// [1024, 1056)  TT   64x64 temporal gram
// [1056, 3104)  NN   128x128 spatial gram tiles
constexpr int BLK_ST = kB * 16;
constexpr int BLK_TS = kB * 16;
constexpr int BLK_TT = kB;
constexpr int BLK_NN = kB * 8 * 8;
constexpr int OFF_TT = BLK_ST + BLK_TS;          // 1024
constexpr int OFF_NN = OFF_TT + BLK_TT;          // 1056
constexpr int BLK_TOTAL = OFF_NN + BLK_NN;       // 3104

// Row stride 36 floats == 4 mod 32 -> 2-way bank alias on column walks (free).
struct SMemGram128 { float A[128][36]; float Bt[32][132]; };
struct SMemGram64  { float A[64][36];  float Bt[32][68];  };
struct SMemMLP {
  union {
    struct { float raw1[64][36]; float raw2[64][36]; } r;  // staged inputs
    struct { float EA[64][36]; float EBt[32][68]; } e;     // exp(-proj)
  } u;
  float w1[64][32];
  float w2v[32];
  float b1v[32];
  float b2v;
};
union SMem { SMemGram128 g; SMemGram64 g64; SMemMLP m; };
}  // namespace

// All component accesses explicit (no (&v.x)[k] address-of patterns -> SROA-safe).
#define FMA4(ACC, AV, B, C)            \
  ACC = fmaf(AV.x, B[0].C, ACC);       \
  ACC = fmaf(AV.y, B[1].C, ACC);       \
  ACC = fmaf(AV.z, B[2].C, ACC);       \
  ACC = fmaf(AV.w, B[3].C, ACC);

#define SIGSTEP(AROW, EAV, EBD, W2D)                                            \
  AROW[0] = fmaf(W2D, __builtin_amdgcn_rcpf(fmaf(EAV, EBD.x, 1.f)), AROW[0]);   \
  AROW[1] = fmaf(W2D, __builtin_amdgcn_rcpf(fmaf(EAV, EBD.y, 1.f)), AROW[1]);   \
  AROW[2] = fmaf(W2D, __builtin_amdgcn_rcpf(fmaf(EAV, EBD.z, 1.f)), AROW[2]);   \
  AROW[3] = fmaf(W2D, __builtin_amdgcn_rcpf(fmaf(EAV, EBD.w, 1.f)), AROW[3]);

// tanh(relu(x)), branchless; exact 0 at x<=0, -> 1 for large x.
__device__ __forceinline__ float tanh_relu(float x) {
  const float xp = fmaxf(x, 0.f);
  const float e = __expf(2.f * xp);
  return 1.f - 2.f * __builtin_amdgcn_rcpf(e + 1.f);
}

__global__ void __launch_bounds__(256)
adj_kernel(const float* __restrict__ sp, const float* __restrict__ tp,
           const float* __restrict__ st_w1, const float* __restrict__ st_b1,
           const float* __restrict__ st_w2, const float* __restrict__ st_b2,
           const float* __restrict__ ts_w1, const float* __restrict__ ts_b1,
           const float* __restrict__ ts_w2, const float* __restrict__ ts_b2,
           float* __restrict__ out) {
  __shared__ SMem sm;
  const int bid = blockIdx.x;
  const int tid = threadIdx.x;
  const int tx = tid & 15;
  const int ty = tid >> 4;

  if (bid >= OFF_NN) {
    // -------- NN: 128x128 spatial gram, 8x8 per thread --------
    const int bid2 = bid - OFF_NN;
    const int b = bid2 >> 6;
    const int t = bid2 & 63;
    const int r0 = (t >> 3) * 128;
    const int c0 = (t & 7) * 128;
    const float* rowp = sp + ((size_t)b * kN + r0) * kD;
    const float* colp = sp + ((size_t)b * kN + c0) * kD;
    for (int q = tid; q < 1024; q += 256) {
      const int r = q >> 3, c = (q & 7) * 4;
      *(float4*)&sm.g.A[r][c] = ((const float4*)rowp)[q];
      const float4 w = ((const float4*)colp)[q];
      sm.g.Bt[c + 0][r] = w.x;
      sm.g.Bt[c + 1][r] = w.y;
      sm.g.Bt[c + 2][r] = w.z;
      sm.g.Bt[c + 3][r] = w.w;
    }
    __syncthreads();
    float acc[8][8] = {};
    #pragma unroll
    for (int k4 = 0; k4 < 8; ++k4) {
      float4 b0[4], b1[4];
      #pragma unroll
      for (int kk = 0; kk < 4; ++kk) {
        b0[kk] = *(const float4*)&sm.g.Bt[k4 * 4 + kk][tx * 4];
        b1[kk] = *(const float4*)&sm.g.Bt[k4 * 4 + kk][64 + tx * 4];
      }
      #pragma unroll
      for (int i = 0; i < 8; ++i) {  // rows ty*4+i (i<4) and 64+ty*4+(i-4)
        const int row = (i & 4) * 16 + ty * 4 + (i & 3);
        const float4 a = *(const float4*)&sm.g.A[row][k4 * 4];
        FMA4(acc[i][0], a, b0, x)
        FMA4(acc[i][1], a, b0, y)
        FMA4(acc[i][2], a, b0, z)
        FMA4(acc[i][3], a, b0, w)
        FMA4(acc[i][4], a, b1, x)
        FMA4(acc[i][5], a, b1, y)
        FMA4(acc[i][6], a, b1, z)
        FMA4(acc[i][7], a, b1, w)
      }
    }
    const size_t base = (size_t)b * kM * kM + (size_t)c0 + tx * 4;
    #pragma unroll
    for (int i = 0; i < 8; ++i) {
      const int r = r0 + (i & 4) * 16 + ty * 4 + (i & 3);
      float4 o0, o1;
      o0.x = tanh_relu(acc[i][0]); o0.y = tanh_relu(acc[i][1]);
      o0.z = tanh_relu(acc[i][2]); o0.w = tanh_relu(acc[i][3]);
      o1.x = tanh_relu(acc[i][4]); o1.y = tanh_relu(acc[i][5]);
      o1.z = tanh_relu(acc[i][6]); o1.w = tanh_relu(acc[i][7]);
      *(float4*)&out[base + (size_t)r * kM] = o0;
      *(float4*)&out[base + (size_t)r * kM + 64] = o1;
    }
  } else if (bid >= OFF_TT) {
    // -------- TT: 64x64 temporal gram, 4x4 per thread --------
    const int b = bid - OFF_TT;
    const float* rowp = tp + (size_t)b * kT * kD;
    for (int q = tid; q < 512; q += 256) {
      const int r = q >> 3, c = (q & 7) * 4;
      const float4 v = ((const float4*)rowp)[q];
      *(float4*)&sm.g64.A[r][c] = v;
      sm.g64.Bt[c + 0][r] = v.x;
      sm.g64.Bt[c + 1][r] = v.y;
      sm.g64.Bt[c + 2][r] = v.z;
      sm.g64.Bt[c + 3][r] = v.w;
    }
    __syncthreads();
    float acc[4][4] = {};
    #pragma unroll
    for (int k4 = 0; k4 < 8; ++k4) {
      float4 b4[4];
      #pragma unroll
      for (int kk = 0; kk < 4; ++kk)
        b4[kk] = *(const float4*)&sm.g64.Bt[k4 * 4 + kk][tx * 4];
      #pragma unroll
      for (int i = 0; i < 4; ++i) {
        const float4 a = *(const float4*)&sm.g64.A[ty * 4 + i][k4 * 4];
        FMA4(acc[i][0], a, b4, x)
        FMA4(acc[i][1], a, b4, y)
        FMA4(acc[i][2], a, b4, z)
        FMA4(acc[i][3], a, b4, w)
      }
    }
    const size_t base = (size_t)b * kM * kM + (size_t)kN + tx * 4;
    #pragma unroll
    for (int i = 0; i < 4; ++i) {
      const int r = kN + ty * 4 + i;
      float4 o;
      o.x = tanh_relu(acc[i][0]);
      o.y = tanh_relu(acc[i][1]);
      o.z = tanh_relu(acc[i][2]);
      o.w = tanh_relu(acc[i][3]);
      *(float4*)&out[base + (size_t)r * kM] = o;
    }
  } else {
    // -------- ST / TS: rank-structured MLP, 64x64 per block --------
    int b, r0, c0;
    const float *rowp, *colp, *w1, *b1, *w2, *b2;
    if (bid < BLK_ST) {
      b = bid >> 4;
      r0 = (bid & 15) * 64; c0 = kN;
      rowp = sp + ((size_t)b * kN + r0) * kD;  // spatial rows (x1)
      colp = tp + (size_t)b * kT * kD;         // temporal cols (x2)
      w1 = st_w1; b1 = st_b1; w2 = st_w2; b2 = st_b2;
    } else {
      const int i = bid - BLK_ST;
      b = i >> 4;
      r0 = kN; c0 = (i & 15) * 64;
      rowp = tp + (size_t)b * kT * kD;          // temporal rows (x1)
      colp = sp + ((size_t)b * kN + c0) * kD;   // spatial cols (x2)
      w1 = ts_w1; b1 = ts_b1; w2 = ts_w2; b2 = ts_b2;
    }
    for (int q = tid; q < 512; q += 256) {
      const int r = q >> 3, c = (q & 7) * 4;
      *(float4*)&sm.m.u.r.raw1[r][c] = ((const float4*)rowp)[q];
      *(float4*)&sm.m.u.r.raw2[r][c] = ((const float4*)colp)[q];
      ((float4*)sm.m.w1)[q] = ((const float4*)w1)[q];
    }
    if (tid < kD) { sm.m.w2v[tid] = w2[tid]; sm.m.b1v[tid] = b1[tid]; }
    if (tid == 0) sm.m.b2v = b2[0];
    __syncthreads();
    // Projections: thread -> (row pr, 8 hidden dims starting at d0).
    const int pr = tid >> 2;
    const int d0 = (tid & 3) * 8;
    float pa[8], pb[8];
    #pragma unroll
    for (int q = 0; q < 8; ++q) { pa[q] = 0.f; pb[q] = sm.m.b1v[d0 + q]; }
    for (int k = 0; k < kD; ++k) {
      const float s1 = sm.m.u.r.raw1[pr][k];
      const float s2 = sm.m.u.r.raw2[pr][k];
      const float4 wa0 = *(const float4*)&sm.m.w1[k][d0];
      const float4 wa1 = *(const float4*)&sm.m.w1[k][d0 + 4];
      const float4 wb0 = *(const float4*)&sm.m.w1[kD + k][d0];
      const float4 wb1 = *(const float4*)&sm.m.w1[kD + k][d0 + 4];
      pa[0] = fmaf(s1, wa0.x, pa[0]); pa[1] = fmaf(s1, wa0.y, pa[1]);
      pa[2] = fmaf(s1, wa0.z, pa[2]); pa[3] = fmaf(s1, wa0.w, pa[3]);
      pa[4] = fmaf(s1, wa1.x, pa[4]); pa[5] = fmaf(s1, wa1.y, pa[5]);
      pa[6] = fmaf(s1, wa1.z, pa[6]); pa[7] = fmaf(s1, wa1.w, pa[7]);
      pb[0] = fmaf(s2, wb0.x, pb[0]); pb[1] = fmaf(s2, wb0.y, pb[1]);
      pb[2] = fmaf(s2, wb0.z, pb[2]); pb[3] = fmaf(s2, wb0.w, pb[3]);
      pb[4] = fmaf(s2, wb1.x, pb[4]); pb[5] = fmaf(s2, wb1.y, pb[5]);
      pb[6] = fmaf(s2, wb1.z, pb[6]); pb[7] = fmaf(s2, wb1.w, pb[7]);
    }
    const float b2s = sm.m.b2v;
    __syncthreads();  // raw reads done; safe to overwrite the union
    #pragma unroll
    for (int q = 0; q < 8; ++q) {
      sm.m.u.e.EA[pr][d0 + q] = __expf(-pa[q]);
      sm.m.u.e.EBt[d0 + q][pr] = __expf(-pb[q]);
    }
    __syncthreads();
    // sigmoid(a+b+b1) = rcp(1 + exp(-a)*exp(-(b+b1))): 1 rcp per term.
    float acc[4][4];
    #pragma unroll
    for (int ii = 0; ii < 4; ++ii) {
      acc[ii][0] = b2s; acc[ii][1] = b2s; acc[ii][2] = b2s; acc[ii][3] = b2s;
    }
    #pragma unroll
    for (int d4 = 0; d4 < 8; ++d4) {
      float4 ea[4];
      #pragma unroll
      for (int ii = 0; ii < 4; ++ii)
        ea[ii] = *(const float4*)&sm.m.u.e.EA[ty * 4 + ii][d4 * 4];
      const float4 eb0 = *(const float4*)&sm.m.u.e.EBt[d4 * 4 + 0][tx * 4];
      const float4 eb1 = *(const float4*)&sm.m.u.e.EBt[d4 * 4 + 1][tx * 4];
      const float4 eb2 = *(const float4*)&sm.m.u.e.EBt[d4 * 4 + 2][tx * 4];
      const float4 eb3 = *(const float4*)&sm.m.u.e.EBt[d4 * 4 + 3][tx * 4];
      const float w20 = sm.m.w2v[d4 * 4 + 0];
      const float w21 = sm.m.w2v[d4 * 4 + 1];
      const float w22 = sm.m.w2v[d4 * 4 + 2];
      const float w23 = sm.m.w2v[d4 * 4 + 3];
      #pragma unroll
      for (int ii = 0; ii < 4; ++ii) {
        SIGSTEP(acc[ii], ea[ii].x, eb0, w20)
        SIGSTEP(acc[ii], ea[ii].y, eb1, w21)
        SIGSTEP(acc[ii], ea[ii].z, eb2, w22)
        SIGSTEP(acc[ii], ea[ii].w, eb3, w23)
      }
    }
    const size_t base = (size_t)b * kM * kM + (size_t)c0 + tx * 4;
    #pragma unroll
    for (int ii = 0; ii < 4; ++ii) {
      const int r = r0 + ty * 4 + ii;
      float4 o;
      o.x = tanh_relu(acc[ii][0]);
      o.y = tanh_relu(acc[ii][1]);
      o.z = tanh_relu(acc[ii][2]);
      o.w = tanh_relu(acc[ii][3]);
      *(float4*)&out[base + (size_t)r * kM] = o;
    }
  }
}

extern "C" void kernel_launch(void* const* d_in, const int* in_sizes, int n_in,
                              void* d_out, int out_size, void* d_ws, size_t ws_size,
                              hipStream_t stream) {
  const float* sp    = (const float*)d_in[0];
  const float* tp    = (const float*)d_in[1];
  const float* st_w1 = (const float*)d_in[2];
  const float* st_b1 = (const float*)d_in[3];
  const float* st_w2 = (const float*)d_in[4];
  const float* st_b2 = (const float*)d_in[5];
  const float* ts_w1 = (const float*)d_in[6];
  const float* ts_b1 = (const float*)d_in[7];
  const float* ts_w2 = (const float*)d_in[8];
  const float* ts_b2 = (const float*)d_in[9];
  float* out = (float*)d_out;
  (void)in_sizes; (void)n_in; (void)out_size; (void)d_ws; (void)ws_size;
  adj_kernel<<<dim3(BLK_TOTAL), dim3(256), 0, stream>>>(
      sp, tp, st_w1, st_b1, st_w2, st_b2, ts_w1, ts_b1, ts_w2, ts_b2, out);
}